// Round 6
// baseline (1405.642 us; speedup 1.0000x reference)
//
#include <hip/hip_runtime.h>

#define NTOK   8192
#define DMODEL 1024
#define NATOM  16384

typedef _Float16 half8  __attribute__((ext_vector_type(8)));
typedef _Float16 half4_t __attribute__((ext_vector_type(4)));
typedef float    f32x4  __attribute__((ext_vector_type(4)));

// async global->LDS, 16B per lane; LDS dest is wave-uniform base + lane*16
#define GLOAD_LDS16(gsrc, ldst) \
  __builtin_amdgcn_global_load_lds((const __attribute__((address_space(1))) unsigned int*)(gsrc), \
                                   (__attribute__((address_space(3))) unsigned int*)(ldst), 16, 0, 0)

// ---------------- prep: fp32 -> fp16 (x only) ----------------
__global__ void cvt_f32_f16(const float* __restrict__ in, _Float16* __restrict__ out, int n4) {
  int i = blockIdx.x * 256 + threadIdx.x;
  if (i >= n4) return;
  float4 v = ((const float4*)in)[i];
  half4_t h;
  h[0] = (_Float16)v.x; h[1] = (_Float16)v.y; h[2] = (_Float16)v.z; h[3] = (_Float16)v.w;
  ((half4_t*)out)[i] = h;
}

// ---------------- prep: dict f32 -> Dh [16384,1024] f16 AND dT [1024,16384] f16 ----------------
__global__ void transpose_dict(const float* __restrict__ dict,
                               _Float16* __restrict__ Dh, _Float16* __restrict__ dT) {
  __shared__ _Float16 tile[64][68];
  int a0 = blockIdx.x * 64;   // atom tile
  int d0 = blockIdx.y * 64;   // dim tile
  int tid = threadIdx.x;
  int c = tid & 63;
  int r0 = tid >> 6;
  #pragma unroll
  for (int i = 0; i < 16; i++) {
    int r = r0 + i * 4;
    _Float16 h = (_Float16)dict[(size_t)(a0 + r) * DMODEL + d0 + c];
    tile[r][c] = h;
    Dh[(size_t)(a0 + r) * DMODEL + d0 + c] = h;
  }
  __syncthreads();
  #pragma unroll
  for (int i = 0; i < 16; i++) {
    int rd = r0 + i * 4;
    dT[(size_t)(d0 + rd) * NATOM + a0 + c] = tile[c][rd];
  }
}

__global__ void zero_lsum(float* __restrict__ lsum) {
  lsum[blockIdx.x * 256 + threadIdx.x] = 0.0f;
}

// 128-row staging helper for recon (proven): 128 rows x 32 k, XOR k-chunk swizzle
__device__ __forceinline__ void stage_ab(const _Float16* __restrict__ A,
                                         const _Float16* __restrict__ B,
                                         _Float16* As, _Float16* Bs,
                                         size_t arow0, size_t brow0, size_t ldk,
                                         int k0, int tid) {
  #pragma unroll
  for (int i = 0; i < 2; i++) {
    int L = tid + i * 256;               // 0..511 = 128 rows x 4 chunks
    int r = L >> 2, pc = L & 3;
    int c = pc ^ ((r >> 1) & 3);
    GLOAD_LDS16(A + (arow0 + r) * ldk + k0 + c * 8, As + (size_t)L * 8);
    GLOAD_LDS16(B + (brow0 + r) * ldk + k0 + c * 8, Bs + (size_t)L * 8);
  }
}

// score staging: one "item" = one k-slot (32 k) of A or B for a 256-row tile = 16 KB,
// lane-linear LDS dest, XOR k-chunk swizzle on the GLOBAL source address.
// XOR granularity is (r>>1)&3 — the round-0 proven 2-way-free pattern (round 5's (r&3)
// was a 4-way bank conflict: 2.6e7 SQ_LDS_BANK_CONFLICT).
__device__ __forceinline__ void stage_item(const _Float16* __restrict__ src, int row0,
                                           int kt, int s, _Float16* dst, int tid) {
  #pragma unroll
  for (int i = 0; i < 2; i++) {
    int L2 = tid + i * 512;              // 0..1023 = 256 rows x 4 chunks
    int r = L2 >> 2, q = L2 & 3;
    int c = s * 4 + (q ^ ((r >> 1) & 3));   // source k-chunk
    GLOAD_LDS16(src + (size_t)(row0 + r) * DMODEL + kt * 64 + c * 8, dst + (size_t)L2 * 8);
  }
}

// ---------------- kernel 1: E = mask ? exp(x @ dict^T) : 0, + row-tile sum/max ----------------
// 256x256 tile, BK=64, 8 waves (2m x 4n), fine-phase schedule (4 phases per K-tile):
// phase p (s=p>>1, mh=p&1) = {ds_read frags, stage 1 item (2 gload_lds), lgkmcnt(0)+SB(0),
// setprio(1), 16 MFMA, setprio(0), [vmcnt(4) at odd phases], s_barrier}.
// LDS k-slot-major per buffer: A_s0|A_s1|B_s0|B_s1 contiguous 16KB items. Items staged
// 3-4 phases ahead of deadline; main loop never drains vmcnt to 0. 128KB LDS, 1 blk/CU.
__launch_bounds__(512, 2)
__global__ void score_kernel(const _Float16* __restrict__ Xh,
                             const _Float16* __restrict__ Dh,
                             const int* __restrict__ mask,
                             _Float16* __restrict__ E,
                             float* __restrict__ lsum,
                             _Float16* __restrict__ Tmax) {   // [8192 tokens][128 tiles]
  __shared__ _Float16 lds[65536];          // 2 bufs x 32768; epilogue reuses 256x136
  const int tid  = threadIdx.x;
  const int lane = tid & 63;
  const int wave = tid >> 6;               // 0..7
  const int wm = wave >> 2;                // 0..1  (128 token rows each)
  const int wn = wave & 3;                 // 0..3  (64 atom cols each)
  const int m0 = blockIdx.y * 256;         // token tile
  const int n0 = blockIdx.x * 256;         // atom tile

  const int frow = lane & 15;
  const int fkc  = lane >> 4;              // k-chunk 0..3 within a 32-k slot

  f32x4 acc[8][4] = {};

  // fragment read offsets; XOR = (ROW>>1)&3 (2-way, conflict-free per m136)
  #define AOFF(B_, S_, ROW_) ((B_) * 32768 + (S_) * 8192 + (((ROW_) << 2) + (fkc ^ (((ROW_) >> 1) & 3))) * 8)
  #define BOFF(B_, S_, ROW_) ((B_) * 32768 + 16384 + (S_) * 8192 + (((ROW_) << 2) + (fkc ^ (((ROW_) >> 1) & 3))) * 8)

  // prologue: stage kt0's 4 items (issue order: A_s0, B_s0, A_s1, B_s1)
  stage_item(Xh, m0, 0, 0, lds,         tid);
  stage_item(Dh, n0, 0, 0, lds + 16384, tid);
  stage_item(Xh, m0, 0, 1, lds + 8192,  tid);
  stage_item(Dh, n0, 0, 1, lds + 24576, tid);
  asm volatile("s_waitcnt vmcnt(4)" ::: "memory");   // s0 items resident; s1 still in flight
  __builtin_amdgcn_s_barrier();

  const int NKT = DMODEL / 64;             // 16
  for (int kt = 0; kt < NKT; ++kt) {
    const int b  = kt & 1;
    const int nb = b ^ 1;
    const bool more = (kt + 1 < NKT);
    half8 af[4], bf[4];

    // ---- phase 0: s=0, mh=0 ----
    #pragma unroll
    for (int i = 0; i < 4; i++) af[i] = *(const half8*)&lds[AOFF(b, 0, wm * 128 + i * 16 + frow)];
    #pragma unroll
    for (int j = 0; j < 4; j++) bf[j] = *(const half8*)&lds[BOFF(b, 0, wn * 64 + j * 16 + frow)];
    if (more) stage_item(Xh, m0, kt + 1, 0, lds + nb * 32768, tid);
    asm volatile("s_waitcnt lgkmcnt(0)" ::: "memory");
    __builtin_amdgcn_sched_barrier(0);
    __builtin_amdgcn_s_setprio(1);
    #pragma unroll
    for (int i = 0; i < 4; i++)
      #pragma unroll
      for (int j = 0; j < 4; j++)
        acc[i][j] = __builtin_amdgcn_mfma_f32_16x16x32_f16(af[i], bf[j], acc[i][j], 0, 0, 0);
    __builtin_amdgcn_s_setprio(0);
    __builtin_amdgcn_sched_barrier(0);
    __builtin_amdgcn_s_barrier();

    // ---- phase 1: s=0, mh=1 (reuse bf) ----
    #pragma unroll
    for (int i = 0; i < 4; i++) af[i] = *(const half8*)&lds[AOFF(b, 0, wm * 128 + 64 + i * 16 + frow)];
    if (more) stage_item(Dh, n0, kt + 1, 0, lds + nb * 32768 + 16384, tid);
    asm volatile("s_waitcnt lgkmcnt(0)" ::: "memory");
    __builtin_amdgcn_sched_barrier(0);
    __builtin_amdgcn_s_setprio(1);
    #pragma unroll
    for (int i = 0; i < 4; i++)
      #pragma unroll
      for (int j = 0; j < 4; j++)
        acc[4 + i][j] = __builtin_amdgcn_mfma_f32_16x16x32_f16(af[i], bf[j], acc[4 + i][j], 0, 0, 0);
    __builtin_amdgcn_s_setprio(0);
    __builtin_amdgcn_sched_barrier(0);
    if (more) asm volatile("s_waitcnt vmcnt(4)" ::: "memory");   // retire this buf's s1 items
    else      asm volatile("s_waitcnt vmcnt(0)" ::: "memory");
    __builtin_amdgcn_s_barrier();

    // ---- phase 2: s=1, mh=0 ----
    #pragma unroll
    for (int i = 0; i < 4; i++) af[i] = *(const half8*)&lds[AOFF(b, 1, wm * 128 + i * 16 + frow)];
    #pragma unroll
    for (int j = 0; j < 4; j++) bf[j] = *(const half8*)&lds[BOFF(b, 1, wn * 64 + j * 16 + frow)];
    if (more) stage_item(Xh, m0, kt + 1, 1, lds + nb * 32768 + 8192, tid);
    asm volatile("s_waitcnt lgkmcnt(0)" ::: "memory");
    __builtin_amdgcn_sched_barrier(0);
    __builtin_amdgcn_s_setprio(1);
    #pragma unroll
    for (int i = 0; i < 4; i++)
      #pragma unroll
      for (int j = 0; j < 4; j++)
        acc[i][j] = __builtin_amdgcn_mfma_f32_16x16x32_f16(af[i], bf[j], acc[i][j], 0, 0, 0);
    __builtin_amdgcn_s_setprio(0);
    __builtin_amdgcn_sched_barrier(0);
    __builtin_amdgcn_s_barrier();

    // ---- phase 3: s=1, mh=1 (reuse bf) ----
    #pragma unroll
    for (int i = 0; i < 4; i++) af[i] = *(const half8*)&lds[AOFF(b, 1, wm * 128 + 64 + i * 16 + frow)];
    if (more) stage_item(Dh, n0, kt + 1, 1, lds + nb * 32768 + 24576, tid);
    asm volatile("s_waitcnt lgkmcnt(0)" ::: "memory");
    __builtin_amdgcn_sched_barrier(0);
    __builtin_amdgcn_s_setprio(1);
    #pragma unroll
    for (int i = 0; i < 4; i++)
      #pragma unroll
      for (int j = 0; j < 4; j++)
        acc[4 + i][j] = __builtin_amdgcn_mfma_f32_16x16x32_f16(af[i], bf[j], acc[4 + i][j], 0, 0, 0);
    __builtin_amdgcn_s_setprio(0);
    __builtin_amdgcn_sched_barrier(0);
    if (more) asm volatile("s_waitcnt vmcnt(4)" ::: "memory");   // retire next buf's s0 items
    __builtin_amdgcn_s_barrier();
  }
  #undef AOFF
  #undef BOFF

  // ---- epilogue, two 128-col passes (pass h = scan tile bx*2+h) ----
  // 1) owner waves write RAW exp to LDS (no mask access here);
  // 2) store pass applies mask via int4x2 vector loads (coalesced, 32 loads/thread total
  //    vs 128 scalar before), writes masked E, and fuses the per-row sum/max reduction
  //    (16-lane shfl tree; each row handled by 16 consecutive lanes of one wave).
  const int cr = (lane >> 4) * 4;
  const int cc = lane & 15;
  #pragma unroll
  for (int h = 0; h < 2; h++) {
    if ((wn >> 1) == h) {
      #pragma unroll
      for (int i = 0; i < 8; i++) {
        #pragma unroll
        for (int j = 0; j < 4; j++) {
          #pragma unroll
          for (int r = 0; r < 4; r++) {
            int lr = wm * 128 + i * 16 + cr + r;          // acc[i] row = i*16 (i 0..7)
            int lc = (wn & 1) * 64 + j * 16 + cc;         // 0..127 within the half
            lds[lr * 136 + lc] = (_Float16)__expf(acc[i][j][r]);   // |s|<=11: exp fits fp16
          }
        }
      }
    }
    __builtin_amdgcn_s_barrier();
    #pragma unroll
    for (int i = 0; i < 8; i++) {
      int chunk = i * 512 + tid;
      int r  = chunk >> 4;                 // 0..255, same r for 16 consecutive tids
      int c8 = (chunk & 15) * 8;
      half8 v = *(const half8*)&lds[r * 136 + c8];
      const int* mp = &mask[(size_t)(m0 + r) * NATOM + n0 + h * 128 + c8];
      int4 k0 = *(const int4*)mp;
      int4 k1 = *(const int4*)(mp + 4);
      half8 e;
      e[0] = k0.x ? v[0] : (_Float16)0.0f;
      e[1] = k0.y ? v[1] : (_Float16)0.0f;
      e[2] = k0.z ? v[2] : (_Float16)0.0f;
      e[3] = k0.w ? v[3] : (_Float16)0.0f;
      e[4] = k1.x ? v[4] : (_Float16)0.0f;
      e[5] = k1.y ? v[5] : (_Float16)0.0f;
      e[6] = k1.z ? v[6] : (_Float16)0.0f;
      e[7] = k1.w ? v[7] : (_Float16)0.0f;
      *(half8*)&E[(size_t)(m0 + r) * NATOM + n0 + h * 128 + c8] = e;
      float s = 0.0f, m = 0.0f;
      #pragma unroll
      for (int j = 0; j < 8; j++) { float f = (float)e[j]; s += f; m = fmaxf(m, f); }
      s += __shfl_xor(s, 1, 64); m = fmaxf(m, __shfl_xor(m, 1, 64));
      s += __shfl_xor(s, 2, 64); m = fmaxf(m, __shfl_xor(m, 2, 64));
      s += __shfl_xor(s, 4, 64); m = fmaxf(m, __shfl_xor(m, 4, 64));
      s += __shfl_xor(s, 8, 64); m = fmaxf(m, __shfl_xor(m, 8, 64));
      if ((tid & 15) == 0) {
        atomicAdd(&lsum[m0 + r], s);
        Tmax[(size_t)(m0 + r) * 128 + blockIdx.x * 2 + h] = (_Float16)m;  // token-major
      }
    }
    __builtin_amdgcn_s_barrier();
  }
}

// ---------------- kernel 2: sparse argmax scan (1 wave / token, 4 tokens / block) ----------------
// Tmax token-major: two contiguous 128B reads/wave. Tiles with max >= 0.98*gmax get their
// 128 E values re-read (margin = 84 sigma of fp16-GEMM error), exact fp64 re-eval,
// ties -> lowest index. Single-wave scope: lockstep, no barriers.
__global__ void scan_lite(const _Float16* __restrict__ E,
                          const _Float16* __restrict__ Tmax,   // [8192][128]
                          const float* __restrict__ x,
                          const float* __restrict__ dict,
                          float* __restrict__ argout) {
  const int wv   = threadIdx.x >> 6;       // 0..3
  const int lane = threadIdx.x & 63;
  const int t = blockIdx.x * 4 + wv;

  __shared__ int    cnt[4];
  __shared__ int    cand[4][32];
  __shared__ double csc[4][32];
  if (lane == 0) cnt[wv] = 0;

  const _Float16* tm = Tmax + (size_t)t * 128;
  float m0 = (float)tm[lane];
  float m1 = (float)tm[64 + lane];
  float mx = fmaxf(m0, m1);
  #pragma unroll
  for (int off = 32; off > 0; off >>= 1) mx = fmaxf(mx, __shfl_xor(mx, off, 64));

  if (mx > 0.0f) {
    float thr = 0.98f * mx;
    unsigned long long q0 = __ballot(m0 >= thr);
    unsigned long long q1 = __ballot(m1 >= thr);
    while (q0 | q1) {
      int tile;
      if (q0) { tile = __ffsll(q0) - 1; q0 &= q0 - 1; }
      else    { tile = 64 + __ffsll(q1) - 1; q1 &= q1 - 1; }
      const _Float16* ep = E + (size_t)t * NATOM + tile * 128;
      float e0 = (float)ep[lane], e1 = (float)ep[64 + lane];
      if (e0 >= thr) { int p = atomicAdd(&cnt[wv], 1); if (p < 32) cand[wv][p] = tile * 128 + lane; }
      if (e1 >= thr) { int p = atomicAdd(&cnt[wv], 1); if (p < 32) cand[wv][p] = tile * 128 + 64 + lane; }
    }
  }
  int nc = min(cnt[wv], 32);
  const float* xr = x + (size_t)t * DMODEL;
  for (int c = 0; c < nc; c++) {
    const float* dr = dict + (size_t)cand[wv][c] * DMODEL;
    double a = 0.0;
    #pragma unroll
    for (int i = 0; i < 16; i++) {
      int d = lane + i * 64;
      a += (double)xr[d] * (double)dr[d];
    }
    #pragma unroll
    for (int off = 32; off > 0; off >>= 1) a += __shfl_down(a, off, 64);
    if (lane == 0) csc[wv][c] = a;
  }
  if (lane == 0) {
    int best = 0;                          // all-masked -> np.argmax of equal values = 0
    if (nc > 0) {
      double bs = -1e300;
      best = NATOM;
      for (int c = 0; c < nc; c++)
        if (csc[wv][c] > bs || (csc[wv][c] == bs && cand[wv][c] < best)) { bs = csc[wv][c]; best = cand[wv][c]; }
    }
    argout[t] = (float)best;               // harness reads d_out as float32
  }
}

// ---------------- kernel 3: recon = (E @ dT^T) / l ----------------
// ROUND-1 FORM (best measured ~430 us): M128 x N128, grid 512 flat with XCD-chunked
// mapping, quad-buffered counted-vmcnt loop (vmcnt(8) steady state), K = 16384 (512 tiles).
__launch_bounds__(256, 2)
__global__ void recon_kernel(const _Float16* __restrict__ E,
                             const _Float16* __restrict__ DT,
                             const float* __restrict__ lsum,
                             float* __restrict__ out) {
  __shared__ _Float16 lds[32768];          // 4 bufs x (As 128x32 + Bs 128x32)
  const int tid  = threadIdx.x;
  const int lane = tid & 63;
  const int wave = tid >> 6;
  const int wm = wave >> 1, wn = wave & 1;
  const int swz = (blockIdx.x & 7) * 64 + (blockIdx.x >> 3);
  const int n0 = (swz & 7) * 128;          // d_model tile
  const int m0 = (swz >> 3) * 128;         // token tile

  const int frow = lane & 15;
  const int fkc  = lane >> 4;

  f32x4 acc[4][4] = {};

  stage_ab(E, DT, lds,         lds + 4096,  m0, n0, NATOM, 0,  tid);
  stage_ab(E, DT, lds + 8192,  lds + 12288, m0, n0, NATOM, 32, tid);
  stage_ab(E, DT, lds + 16384, lds + 20480, m0, n0, NATOM, 64, tid);

  for (int t = 0; t < 512; ++t) {
    if (t < 510)       asm volatile("s_waitcnt vmcnt(8)" ::: "memory");
    else if (t == 510) asm volatile("s_waitcnt vmcnt(4)" ::: "memory");
    else               asm volatile("s_waitcnt vmcnt(0)" ::: "memory");
    __builtin_amdgcn_s_barrier();
    __builtin_amdgcn_sched_barrier(0);
    const _Float16* As = lds + (t & 3) * 8192;
    const _Float16* Bs = As + 4096;
    half8 af[4], bf[4];
    #pragma unroll
    for (int i = 0; i < 4; i++) {
      int ar = wm * 64 + i * 16 + frow;
      int br = wn * 64 + i * 16 + frow;
      af[i] = *(const half8*)&As[ar * 32 + ((fkc ^ ((ar >> 1) & 3)) << 3)];
      bf[i] = *(const half8*)&Bs[br * 32 + ((fkc ^ ((br >> 1) & 3)) << 3)];
    }
    if (t + 3 < 512) {
      int b = (t + 3) & 3;
      stage_ab(E, DT, lds + b * 8192, lds + b * 8192 + 4096, m0, n0, NATOM, (t + 3) * 32, tid);
    }
    __builtin_amdgcn_s_setprio(1);
    #pragma unroll
    for (int i = 0; i < 4; i++)
      #pragma unroll
      for (int j = 0; j < 4; j++)
        acc[i][j] = __builtin_amdgcn_mfma_f32_16x16x32_f16(af[i], bf[j], acc[i][j], 0, 0, 0);
    __builtin_amdgcn_s_setprio(0);
    __builtin_amdgcn_sched_barrier(0);
  }

  const int cr = (lane >> 4) * 4;
  const int cc = lane & 15;
  #pragma unroll
  for (int i = 0; i < 4; i++) {
    #pragma unroll
    for (int r = 0; r < 4; r++) {
      int lr = wm * 64 + i * 16 + cr + r;
      float sc = 1.0f / lsum[m0 + lr];
      #pragma unroll
      for (int j = 0; j < 4; j++) {
        int lc = wn * 64 + j * 16 + cc;
        out[(size_t)(m0 + lr) * DMODEL + (n0 + lc)] = acc[i][j][r] * sc;
      }
    }
  }
}

extern "C" void kernel_launch(void* const* d_in, const int* in_sizes, int n_in,
                              void* d_out, int out_size, void* d_ws, size_t ws_size,
                              hipStream_t stream) {
  const float* x    = (const float*)d_in[0];
  const float* dict = (const float*)d_in[1];
  const int*   mask = (const int*)d_in[2];
  float* recon  = (float*)d_out;
  float* argout = recon + (size_t)NTOK * DMODEL;

  // workspace layout (336 MB + 32 KB — proven size)
  char* w = (char*)d_ws;
  _Float16* Xh = (_Float16*)(w);                                 // 16 MB  [8192,1024]
  _Float16* Dh = (_Float16*)(w + (size_t)16  * 1024 * 1024);     // 32 MB  [16384,1024]
  _Float16* DT = (_Float16*)(w + (size_t)48  * 1024 * 1024);     // 32 MB  [1024,16384]
  _Float16* E  = (_Float16*)(w + (size_t)80  * 1024 * 1024);     // 256 MB [8192,16384]
  float*  lsum = (float*)  (w + (size_t)336 * 1024 * 1024);      // 32 KB
  // Tmax (2 MB fp16, token-major [8192][128]) borrows the front of d_out's recon region;
  // scan_lite consumes it before recon_kernel overwrites the region (stream-serialized).
  _Float16* Tmax = (_Float16*)d_out;

  cvt_f32_f16<<<dim3(NTOK * DMODEL / 4 / 256), 256, 0, stream>>>(x, Xh, NTOK * DMODEL / 4);
  transpose_dict<<<dim3(NATOM / 64, DMODEL / 64), 256, 0, stream>>>(dict, Dh, DT);
  zero_lsum<<<dim3(NTOK / 256), 256, 0, stream>>>(lsum);
  score_kernel<<<dim3(NATOM / 256, NTOK / 256), 512, 0, stream>>>(Xh, Dh, mask, E, lsum, Tmax);
  scan_lite<<<dim3(NTOK / 4), 256, 0, stream>>>(E, Tmax, x, dict, argout);
  recon_kernel<<<dim3(512), 256, 0, stream>>>(E, DT, lsum, recon);
}

// Round 7
// 1360.551 us; speedup vs baseline: 1.0331x; 1.0331x over previous
//
#include <hip/hip_runtime.h>

#define NTOK   8192
#define DMODEL 1024
#define NATOM  16384

typedef _Float16 half8  __attribute__((ext_vector_type(8)));
typedef _Float16 half4_t __attribute__((ext_vector_type(4)));
typedef float    f32x4  __attribute__((ext_vector_type(4)));

// async global->LDS, 16B per lane; LDS dest is wave-uniform base + lane*16
#define GLOAD_LDS16(gsrc, ldst) \
  __builtin_amdgcn_global_load_lds((const __attribute__((address_space(1))) unsigned int*)(gsrc), \
                                   (__attribute__((address_space(3))) unsigned int*)(ldst), 16, 0, 0)

// ---------------- prep: fp32 -> fp16 (x only) ----------------
__global__ void cvt_f32_f16(const float* __restrict__ in, _Float16* __restrict__ out, int n4) {
  int i = blockIdx.x * 256 + threadIdx.x;
  if (i >= n4) return;
  float4 v = ((const float4*)in)[i];
  half4_t h;
  h[0] = (_Float16)v.x; h[1] = (_Float16)v.y; h[2] = (_Float16)v.z; h[3] = (_Float16)v.w;
  ((half4_t*)out)[i] = h;
}

// ---------------- prep: dict f32 -> Dh [16384,1024] f16 AND dT [1024,16384] f16 ----------------
__global__ void transpose_dict(const float* __restrict__ dict,
                               _Float16* __restrict__ Dh, _Float16* __restrict__ dT) {
  __shared__ _Float16 tile[64][68];
  int a0 = blockIdx.x * 64;   // atom tile
  int d0 = blockIdx.y * 64;   // dim tile
  int tid = threadIdx.x;
  int c = tid & 63;
  int r0 = tid >> 6;
  #pragma unroll
  for (int i = 0; i < 16; i++) {
    int r = r0 + i * 4;
    _Float16 h = (_Float16)dict[(size_t)(a0 + r) * DMODEL + d0 + c];
    tile[r][c] = h;
    Dh[(size_t)(a0 + r) * DMODEL + d0 + c] = h;
  }
  __syncthreads();
  #pragma unroll
  for (int i = 0; i < 16; i++) {
    int rd = r0 + i * 4;
    dT[(size_t)(d0 + rd) * NATOM + a0 + c] = tile[c][rd];
  }
}

__global__ void zero_lsum(float* __restrict__ lsum) {
  lsum[blockIdx.x * 256 + threadIdx.x] = 0.0f;
}

// score staging (PROVEN r6): one "item" = one k-slot (32 k) of a 256-row tile = 16 KB,
// lane-linear LDS dest, XOR k-chunk swizzle (r>>1)&3 on the GLOBAL source address.
__device__ __forceinline__ void stage_item(const _Float16* __restrict__ src, int row0,
                                           int kt, int s, _Float16* dst, int tid) {
  #pragma unroll
  for (int i = 0; i < 2; i++) {
    int L2 = tid + i * 512;              // 0..1023 = 256 rows x 4 chunks
    int r = L2 >> 2, q = L2 & 3;
    int c = s * 4 + (q ^ ((r >> 1) & 3));   // source k-chunk
    GLOAD_LDS16(src + (size_t)(row0 + r) * DMODEL + kt * 64 + c * 8, dst + (size_t)L2 * 8);
  }
}

// recon staging: same pattern, generalized row-count/leading-dim.
// 256-row item (16 KB, 2 loads/thread):
__device__ __forceinline__ void rstage256(const _Float16* __restrict__ src, int row0,
                                          size_t ldk, int k0, int s, _Float16* dst, int tid) {
  #pragma unroll
  for (int i = 0; i < 2; i++) {
    int L2 = tid + i * 512;              // 0..1023 = 256 rows x 4 chunks
    int r = L2 >> 2, q = L2 & 3;
    int c = s * 4 + (q ^ ((r >> 1) & 3));
    GLOAD_LDS16(src + (size_t)(row0 + r) * ldk + k0 + c * 8, dst + (size_t)L2 * 8);
  }
}
// 128-row item (8 KB, 1 load/thread):
__device__ __forceinline__ void rstage128(const _Float16* __restrict__ src, int row0,
                                          size_t ldk, int k0, int s, _Float16* dst, int tid) {
  int L = tid;                           // 0..511 = 128 rows x 4 chunks
  int r = L >> 2, q = L & 3;
  int c = s * 4 + (q ^ ((r >> 1) & 3));
  GLOAD_LDS16(src + (size_t)(row0 + r) * ldk + k0 + c * 8, dst + (size_t)L * 8);
}

// ---------------- kernel 1: score (ROUND-6 VERBATIM, best measured 427 us) ----------------
__launch_bounds__(512, 2)
__global__ void score_kernel(const _Float16* __restrict__ Xh,
                             const _Float16* __restrict__ Dh,
                             const int* __restrict__ mask,
                             _Float16* __restrict__ E,
                             float* __restrict__ lsum,
                             _Float16* __restrict__ Tmax) {   // [8192 tokens][128 tiles]
  __shared__ _Float16 lds[65536];          // 2 bufs x 32768; epilogue reuses 256x136
  const int tid  = threadIdx.x;
  const int lane = tid & 63;
  const int wave = tid >> 6;               // 0..7
  const int wm = wave >> 2;                // 0..1  (128 token rows each)
  const int wn = wave & 3;                 // 0..3  (64 atom cols each)
  const int m0 = blockIdx.y * 256;         // token tile
  const int n0 = blockIdx.x * 256;         // atom tile

  const int frow = lane & 15;
  const int fkc  = lane >> 4;              // k-chunk 0..3 within a 32-k slot

  f32x4 acc[8][4] = {};

  #define AOFF(B_, S_, ROW_) ((B_) * 32768 + (S_) * 8192 + (((ROW_) << 2) + (fkc ^ (((ROW_) >> 1) & 3))) * 8)
  #define BOFF(B_, S_, ROW_) ((B_) * 32768 + 16384 + (S_) * 8192 + (((ROW_) << 2) + (fkc ^ (((ROW_) >> 1) & 3))) * 8)

  stage_item(Xh, m0, 0, 0, lds,         tid);
  stage_item(Dh, n0, 0, 0, lds + 16384, tid);
  stage_item(Xh, m0, 0, 1, lds + 8192,  tid);
  stage_item(Dh, n0, 0, 1, lds + 24576, tid);
  asm volatile("s_waitcnt vmcnt(4)" ::: "memory");   // s0 items resident; s1 still in flight
  __builtin_amdgcn_s_barrier();

  const int NKT = DMODEL / 64;             // 16
  for (int kt = 0; kt < NKT; ++kt) {
    const int b  = kt & 1;
    const int nb = b ^ 1;
    const bool more = (kt + 1 < NKT);
    half8 af[4], bf[4];

    // ---- phase 0: s=0, mh=0 ----
    #pragma unroll
    for (int i = 0; i < 4; i++) af[i] = *(const half8*)&lds[AOFF(b, 0, wm * 128 + i * 16 + frow)];
    #pragma unroll
    for (int j = 0; j < 4; j++) bf[j] = *(const half8*)&lds[BOFF(b, 0, wn * 64 + j * 16 + frow)];
    if (more) stage_item(Xh, m0, kt + 1, 0, lds + nb * 32768, tid);
    asm volatile("s_waitcnt lgkmcnt(0)" ::: "memory");
    __builtin_amdgcn_sched_barrier(0);
    __builtin_amdgcn_s_setprio(1);
    #pragma unroll
    for (int i = 0; i < 4; i++)
      #pragma unroll
      for (int j = 0; j < 4; j++)
        acc[i][j] = __builtin_amdgcn_mfma_f32_16x16x32_f16(af[i], bf[j], acc[i][j], 0, 0, 0);
    __builtin_amdgcn_s_setprio(0);
    __builtin_amdgcn_sched_barrier(0);
    __builtin_amdgcn_s_barrier();

    // ---- phase 1: s=0, mh=1 (reuse bf) ----
    #pragma unroll
    for (int i = 0; i < 4; i++) af[i] = *(const half8*)&lds[AOFF(b, 0, wm * 128 + 64 + i * 16 + frow)];
    if (more) stage_item(Dh, n0, kt + 1, 0, lds + nb * 32768 + 16384, tid);
    asm volatile("s_waitcnt lgkmcnt(0)" ::: "memory");
    __builtin_amdgcn_sched_barrier(0);
    __builtin_amdgcn_s_setprio(1);
    #pragma unroll
    for (int i = 0; i < 4; i++)
      #pragma unroll
      for (int j = 0; j < 4; j++)
        acc[4 + i][j] = __builtin_amdgcn_mfma_f32_16x16x32_f16(af[i], bf[j], acc[4 + i][j], 0, 0, 0);
    __builtin_amdgcn_s_setprio(0);
    __builtin_amdgcn_sched_barrier(0);
    if (more) asm volatile("s_waitcnt vmcnt(4)" ::: "memory");   // retire this buf's s1 items
    else      asm volatile("s_waitcnt vmcnt(0)" ::: "memory");
    __builtin_amdgcn_s_barrier();

    // ---- phase 2: s=1, mh=0 ----
    #pragma unroll
    for (int i = 0; i < 4; i++) af[i] = *(const half8*)&lds[AOFF(b, 1, wm * 128 + i * 16 + frow)];
    #pragma unroll
    for (int j = 0; j < 4; j++) bf[j] = *(const half8*)&lds[BOFF(b, 1, wn * 64 + j * 16 + frow)];
    if (more) stage_item(Xh, m0, kt + 1, 1, lds + nb * 32768 + 8192, tid);
    asm volatile("s_waitcnt lgkmcnt(0)" ::: "memory");
    __builtin_amdgcn_sched_barrier(0);
    __builtin_amdgcn_s_setprio(1);
    #pragma unroll
    for (int i = 0; i < 4; i++)
      #pragma unroll
      for (int j = 0; j < 4; j++)
        acc[i][j] = __builtin_amdgcn_mfma_f32_16x16x32_f16(af[i], bf[j], acc[i][j], 0, 0, 0);
    __builtin_amdgcn_s_setprio(0);
    __builtin_amdgcn_sched_barrier(0);
    __builtin_amdgcn_s_barrier();

    // ---- phase 3: s=1, mh=1 (reuse bf) ----
    #pragma unroll
    for (int i = 0; i < 4; i++) af[i] = *(const half8*)&lds[AOFF(b, 1, wm * 128 + 64 + i * 16 + frow)];
    if (more) stage_item(Dh, n0, kt + 1, 1, lds + nb * 32768 + 24576, tid);
    asm volatile("s_waitcnt lgkmcnt(0)" ::: "memory");
    __builtin_amdgcn_sched_barrier(0);
    __builtin_amdgcn_s_setprio(1);
    #pragma unroll
    for (int i = 0; i < 4; i++)
      #pragma unroll
      for (int j = 0; j < 4; j++)
        acc[4 + i][j] = __builtin_amdgcn_mfma_f32_16x16x32_f16(af[i], bf[j], acc[4 + i][j], 0, 0, 0);
    __builtin_amdgcn_s_setprio(0);
    __builtin_amdgcn_sched_barrier(0);
    if (more) asm volatile("s_waitcnt vmcnt(4)" ::: "memory");   // retire next buf's s0 items
    __builtin_amdgcn_s_barrier();
  }
  #undef AOFF
  #undef BOFF

  // epilogue (r6): raw exp -> LDS; store pass applies mask via int4x2 + fused reduce
  const int cr = (lane >> 4) * 4;
  const int cc = lane & 15;
  #pragma unroll
  for (int h = 0; h < 2; h++) {
    if ((wn >> 1) == h) {
      #pragma unroll
      for (int i = 0; i < 8; i++) {
        #pragma unroll
        for (int j = 0; j < 4; j++) {
          #pragma unroll
          for (int r = 0; r < 4; r++) {
            int lr = wm * 128 + i * 16 + cr + r;
            int lc = (wn & 1) * 64 + j * 16 + cc;
            lds[lr * 136 + lc] = (_Float16)__expf(acc[i][j][r]);   // |s|<=11: exp fits fp16
          }
        }
      }
    }
    __builtin_amdgcn_s_barrier();
    #pragma unroll
    for (int i = 0; i < 8; i++) {
      int chunk = i * 512 + tid;
      int r  = chunk >> 4;
      int c8 = (chunk & 15) * 8;
      half8 v = *(const half8*)&lds[r * 136 + c8];
      const int* mp = &mask[(size_t)(m0 + r) * NATOM + n0 + h * 128 + c8];
      int4 k0 = *(const int4*)mp;
      int4 k1 = *(const int4*)(mp + 4);
      half8 e;
      e[0] = k0.x ? v[0] : (_Float16)0.0f;
      e[1] = k0.y ? v[1] : (_Float16)0.0f;
      e[2] = k0.z ? v[2] : (_Float16)0.0f;
      e[3] = k0.w ? v[3] : (_Float16)0.0f;
      e[4] = k1.x ? v[4] : (_Float16)0.0f;
      e[5] = k1.y ? v[5] : (_Float16)0.0f;
      e[6] = k1.z ? v[6] : (_Float16)0.0f;
      e[7] = k1.w ? v[7] : (_Float16)0.0f;
      *(half8*)&E[(size_t)(m0 + r) * NATOM + n0 + h * 128 + c8] = e;
      float s = 0.0f, m = 0.0f;
      #pragma unroll
      for (int j = 0; j < 8; j++) { float f = (float)e[j]; s += f; m = fmaxf(m, f); }
      s += __shfl_xor(s, 1, 64); m = fmaxf(m, __shfl_xor(m, 1, 64));
      s += __shfl_xor(s, 2, 64); m = fmaxf(m, __shfl_xor(m, 2, 64));
      s += __shfl_xor(s, 4, 64); m = fmaxf(m, __shfl_xor(m, 4, 64));
      s += __shfl_xor(s, 8, 64); m = fmaxf(m, __shfl_xor(m, 8, 64));
      if ((tid & 15) == 0) {
        atomicAdd(&lsum[m0 + r], s);
        Tmax[(size_t)(m0 + r) * 128 + blockIdx.x * 2 + h] = (_Float16)m;  // token-major
      }
    }
    __builtin_amdgcn_s_barrier();
  }
}

// ---------------- kernel 2: sparse argmax scan (unchanged r6) ----------------
__global__ void scan_lite(const _Float16* __restrict__ E,
                          const _Float16* __restrict__ Tmax,   // [8192][128]
                          const float* __restrict__ x,
                          const float* __restrict__ dict,
                          float* __restrict__ argout) {
  const int wv   = threadIdx.x >> 6;       // 0..3
  const int lane = threadIdx.x & 63;
  const int t = blockIdx.x * 4 + wv;

  __shared__ int    cnt[4];
  __shared__ int    cand[4][32];
  __shared__ double csc[4][32];
  if (lane == 0) cnt[wv] = 0;

  const _Float16* tm = Tmax + (size_t)t * 128;
  float m0 = (float)tm[lane];
  float m1 = (float)tm[64 + lane];
  float mx = fmaxf(m0, m1);
  #pragma unroll
  for (int off = 32; off > 0; off >>= 1) mx = fmaxf(mx, __shfl_xor(mx, off, 64));

  if (mx > 0.0f) {
    float thr = 0.98f * mx;
    unsigned long long q0 = __ballot(m0 >= thr);
    unsigned long long q1 = __ballot(m1 >= thr);
    while (q0 | q1) {
      int tile;
      if (q0) { tile = __ffsll(q0) - 1; q0 &= q0 - 1; }
      else    { tile = 64 + __ffsll(q1) - 1; q1 &= q1 - 1; }
      const _Float16* ep = E + (size_t)t * NATOM + tile * 128;
      float e0 = (float)ep[lane], e1 = (float)ep[64 + lane];
      if (e0 >= thr) { int p = atomicAdd(&cnt[wv], 1); if (p < 32) cand[wv][p] = tile * 128 + lane; }
      if (e1 >= thr) { int p = atomicAdd(&cnt[wv], 1); if (p < 32) cand[wv][p] = tile * 128 + 64 + lane; }
    }
  }
  int nc = min(cnt[wv], 32);
  const float* xr = x + (size_t)t * DMODEL;
  for (int c = 0; c < nc; c++) {
    const float* dr = dict + (size_t)cand[wv][c] * DMODEL;
    double a = 0.0;
    #pragma unroll
    for (int i = 0; i < 16; i++) {
      int d = lane + i * 64;
      a += (double)xr[d] * (double)dr[d];
    }
    #pragma unroll
    for (int off = 32; off > 0; off >>= 1) a += __shfl_down(a, off, 64);
    if (lane == 0) csc[wv][c] = a;
  }
  if (lane == 0) {
    int best = 0;                          // all-masked -> np.argmax of equal values = 0
    if (nc > 0) {
      double bs = -1e300;
      best = NATOM;
      for (int c = 0; c < nc; c++)
        if (csc[wv][c] > bs || (csc[wv][c] == bs && cand[wv][c] < best)) { bs = csc[wv][c]; best = cand[wv][c]; }
    }
    argout[t] = (float)best;               // harness reads d_out as float32
  }
}

// ---------------- kernel 3: recon = (E @ dT^T) / l ----------------
// NEW: fine-phase port of score-r6's proven K-loop. BM=256 x BN=128, BK=64, K=16384
// (256 K-tiles), 8 waves (2m x 4n -> 128x32 per wave), acc[8][2], 2 bufs x 48 KB LDS,
// counted vmcnt(3) steady state. Grid 256 = 1 block/CU; XCD map: XCD k owns m-tiles
// [4k,4k+4) x all 8 n-tiles (its 8 n-blocks share each 8 MB E panel through L2).
__launch_bounds__(512, 2)
__global__ void recon_kernel(const _Float16* __restrict__ E,
                             const _Float16* __restrict__ DT,
                             const float* __restrict__ lsum,
                             float* __restrict__ out) {
  __shared__ _Float16 lds[49152];   // 2 bufs x (A_s0 8192 | A_s1 8192 | B_s0 4096 | B_s1 4096)
  const int tid  = threadIdx.x;
  const int lane = tid & 63;
  const int wave = tid >> 6;
  const int wm = wave >> 2;         // 0..1 -> 128 token rows
  const int wn = wave & 3;          // 0..3 -> 32 dmodel cols
  const int bid = blockIdx.x;
  const int xcd = bid & 7;
  const int idx = bid >> 3;         // 0..31
  const int mt  = xcd * 4 + (idx & 3);   // token tile 0..31
  const int nt  = idx >> 2;              // dmodel tile 0..7
  const int m0 = mt * 256;
  const int n0 = nt * 128;

  const int frow = lane & 15;
  const int fkc  = lane >> 4;

  f32x4 acc[8][2] = {};

  #define RAOFF(B_, S_, ROW_) ((B_) * 24576 + (S_) * 8192 + (((ROW_) << 2) + (fkc ^ (((ROW_) >> 1) & 3))) * 8)
  #define RBOFF(B_, S_, ROW_) ((B_) * 24576 + 16384 + (S_) * 4096 + (((ROW_) << 2) + (fkc ^ (((ROW_) >> 1) & 3))) * 8)

  // prologue: kt0's items (A_s0 2ops, B_s0 1op, A_s1 2ops, B_s1 1op)
  rstage256(E,  m0, NATOM, 0, 0, lds,         tid);
  rstage128(DT, n0, NATOM, 0, 0, lds + 16384, tid);
  rstage256(E,  m0, NATOM, 0, 1, lds + 8192,  tid);
  rstage128(DT, n0, NATOM, 0, 1, lds + 20480, tid);
  asm volatile("s_waitcnt vmcnt(3)" ::: "memory");   // s0 (3 ops) resident; s1 in flight
  __builtin_amdgcn_s_barrier();

  const int NKT = NATOM / 64;       // 256
  for (int kt = 0; kt < NKT; ++kt) {
    const int b  = kt & 1;
    const int nb = b ^ 1;
    const bool more = (kt + 1 < NKT);
    const int k1 = (kt + 1) * 64;
    half8 af[4], bf[2];

    // ---- phase 0: s=0, mh=0 ----
    #pragma unroll
    for (int i = 0; i < 4; i++) af[i] = *(const half8*)&lds[RAOFF(b, 0, wm * 128 + i * 16 + frow)];
    #pragma unroll
    for (int j = 0; j < 2; j++) bf[j] = *(const half8*)&lds[RBOFF(b, 0, wn * 32 + j * 16 + frow)];
    if (more) rstage256(E, m0, NATOM, k1, 0, lds + nb * 24576, tid);
    asm volatile("s_waitcnt lgkmcnt(0)" ::: "memory");
    __builtin_amdgcn_sched_barrier(0);
    __builtin_amdgcn_s_setprio(1);
    #pragma unroll
    for (int i = 0; i < 4; i++)
      #pragma unroll
      for (int j = 0; j < 2; j++)
        acc[i][j] = __builtin_amdgcn_mfma_f32_16x16x32_f16(af[i], bf[j], acc[i][j], 0, 0, 0);
    __builtin_amdgcn_s_setprio(0);
    __builtin_amdgcn_sched_barrier(0);
    __builtin_amdgcn_s_barrier();

    // ---- phase 1: s=0, mh=1 (reuse bf) ----
    #pragma unroll
    for (int i = 0; i < 4; i++) af[i] = *(const half8*)&lds[RAOFF(b, 0, wm * 128 + 64 + i * 16 + frow)];
    if (more) rstage128(DT, n0, NATOM, k1, 0, lds + nb * 24576 + 16384, tid);
    asm volatile("s_waitcnt lgkmcnt(0)" ::: "memory");
    __builtin_amdgcn_sched_barrier(0);
    __builtin_amdgcn_s_setprio(1);
    #pragma unroll
    for (int i = 0; i < 4; i++)
      #pragma unroll
      for (int j = 0; j < 2; j++)
        acc[4 + i][j] = __builtin_amdgcn_mfma_f32_16x16x32_f16(af[i], bf[j], acc[4 + i][j], 0, 0, 0);
    __builtin_amdgcn_s_setprio(0);
    __builtin_amdgcn_sched_barrier(0);
    if (more) asm volatile("s_waitcnt vmcnt(3)" ::: "memory");   // retire this buf's s1 items
    else      asm volatile("s_waitcnt vmcnt(0)" ::: "memory");
    __builtin_amdgcn_s_barrier();

    // ---- phase 2: s=1, mh=0 ----
    #pragma unroll
    for (int i = 0; i < 4; i++) af[i] = *(const half8*)&lds[RAOFF(b, 1, wm * 128 + i * 16 + frow)];
    #pragma unroll
    for (int j = 0; j < 2; j++) bf[j] = *(const half8*)&lds[RBOFF(b, 1, wn * 32 + j * 16 + frow)];
    if (more) rstage256(E, m0, NATOM, k1, 1, lds + nb * 24576 + 8192, tid);
    asm volatile("s_waitcnt lgkmcnt(0)" ::: "memory");
    __builtin_amdgcn_sched_barrier(0);
    __builtin_amdgcn_s_setprio(1);
    #pragma unroll
    for (int i = 0; i < 4; i++)
      #pragma unroll
      for (int j = 0; j < 2; j++)
        acc[i][j] = __builtin_amdgcn_mfma_f32_16x16x32_f16(af[i], bf[j], acc[i][j], 0, 0, 0);
    __builtin_amdgcn_s_setprio(0);
    __builtin_amdgcn_sched_barrier(0);
    __builtin_amdgcn_s_barrier();

    // ---- phase 3: s=1, mh=1 (reuse bf) ----
    #pragma unroll
    for (int i = 0; i < 4; i++) af[i] = *(const half8*)&lds[RAOFF(b, 1, wm * 128 + 64 + i * 16 + frow)];
    if (more) rstage128(DT, n0, NATOM, k1, 1, lds + nb * 24576 + 20480, tid);
    asm volatile("s_waitcnt lgkmcnt(0)" ::: "memory");
    __builtin_amdgcn_sched_barrier(0);
    __builtin_amdgcn_s_setprio(1);
    #pragma unroll
    for (int i = 0; i < 4; i++)
      #pragma unroll
      for (int j = 0; j < 2; j++)
        acc[4 + i][j] = __builtin_amdgcn_mfma_f32_16x16x32_f16(af[i], bf[j], acc[4 + i][j], 0, 0, 0);
    __builtin_amdgcn_s_setprio(0);
    __builtin_amdgcn_sched_barrier(0);
    if (more) asm volatile("s_waitcnt vmcnt(3)" ::: "memory");   // retire next buf's s0 items
    __builtin_amdgcn_s_barrier();
  }
  #undef RAOFF
  #undef RBOFF

  // epilogue: direct store. acc[mh*4+i][j] -> row wm*128 + mh*64 + i*16 + cr + r,
  // col wn*32 + j*16 + cc.
  const int cr = (lane >> 4) * 4;
  const int cc = lane & 15;
  #pragma unroll
  for (int a = 0; a < 8; a++) {
    int rowbase = wm * 128 + (a >> 2) * 64 + (a & 3) * 16 + cr;
    #pragma unroll
    for (int r = 0; r < 4; r++) {
      int lr = rowbase + r;
      float sc = 1.0f / lsum[m0 + lr];
      #pragma unroll
      for (int j = 0; j < 2; j++) {
        int lc = wn * 32 + j * 16 + cc;
        out[(size_t)(m0 + lr) * DMODEL + (n0 + lc)] = acc[a][j][r] * sc;
      }
    }
  }
}

extern "C" void kernel_launch(void* const* d_in, const int* in_sizes, int n_in,
                              void* d_out, int out_size, void* d_ws, size_t ws_size,
                              hipStream_t stream) {
  const float* x    = (const float*)d_in[0];
  const float* dict = (const float*)d_in[1];
  const int*   mask = (const int*)d_in[2];
  float* recon  = (float*)d_out;
  float* argout = recon + (size_t)NTOK * DMODEL;

  // workspace layout (336 MB + 32 KB — proven size)
  char* w = (char*)d_ws;
  _Float16* Xh = (_Float16*)(w);                                 // 16 MB  [8192,1024]
  _Float16* Dh = (_Float16*)(w + (size_t)16  * 1024 * 1024);     // 32 MB  [16384,1024]
  _Float16* DT = (_Float16*)(w + (size_t)48  * 1024 * 1024);     // 32 MB  [1024,16384]
  _Float16* E  = (_Float16*)(w + (size_t)80  * 1024 * 1024);     // 256 MB [8192,16384]
  float*  lsum = (float*)  (w + (size_t)336 * 1024 * 1024);      // 32 KB
  // Tmax (2 MB fp16, token-major [8192][128]) borrows the front of d_out's recon region;
  // scan_lite consumes it before recon_kernel overwrites the region (stream-serialized).
  _Float16* Tmax = (_Float16*)d_out;

  cvt_f32_f16<<<dim3(NTOK * DMODEL / 4 / 256), 256, 0, stream>>>(x, Xh, NTOK * DMODEL / 4);
  transpose_dict<<<dim3(NATOM / 64, DMODEL / 64), 256, 0, stream>>>(dict, Dh, DT);
  zero_lsum<<<dim3(NTOK / 256), 256, 0, stream>>>(lsum);
  score_kernel<<<dim3(NATOM / 256, NTOK / 256), 512, 0, stream>>>(Xh, Dh, mask, E, lsum, Tmax);
  scan_lite<<<dim3(NTOK / 4), 256, 0, stream>>>(E, Tmax, x, dict, argout);
  recon_kernel<<<dim3(256), 512, 0, stream>>>(E, DT, lsum, recon);
}